// Round 12
// baseline (124.281 us; speedup 1.0000x reference)
//
#include <hip/hip_runtime.h>

#define D 128
#define NPB 256            // nodes per bucket (dst>>8)
#define NBMAX 512          // max buckets (N <= 131072)
#define BKCAP 8192         // edge capacity per bucket (mean 4096, +64 sigma)
#define CHUNK 8192         // edges per scatter block
#define OVF_CAP 8192

typedef __attribute__((ext_vector_type(8))) short short8x;
typedef __attribute__((ext_vector_type(4))) float f32x4;

// ---- bf16 helpers (manual RNE) ----
__device__ inline unsigned int f2bf(float f) {
    unsigned int u = __builtin_bit_cast(unsigned int, f);
    return (u + 0x7fffu + ((u >> 16) & 1u)) >> 16;
}
__device__ inline float bflo(unsigned int v) {
    return __builtin_bit_cast(float, v << 16);
}
__device__ inline float bfhi(unsigned int v) {
    return __builtin_bit_cast(float, v & 0xffff0000u);
}
__device__ inline unsigned int pack2(float lo, float hi) {
    return f2bf(lo) | (f2bf(hi) << 16);
}

// ========= W pre-pack (+ block 16 zeroes gfill/ovfc) =========
__global__ __launch_bounds__(256) void pack_w(
    const float* __restrict__ W1, const float* __restrict__ W2,
    uint4* __restrict__ pack, int* __restrict__ zero_area, int nz)
{
    if (blockIdx.x == 16) {
        for (int i = threadIdx.x; i < nz; i += 256) zero_area[i] = 0;
        return;
    }
    int e = blockIdx.x * 256 + threadIdx.x;      // 0..4095
    const float* W = (e & 2048) ? W2 : W1;
    int f = (e >> 6) & 31, l = e & 63;
    int kt = f >> 3, nt = f & 7;
    int k0 = kt * 32 + (l >> 4) * 8;
    int col = nt * 16 + (l & 15);
    unsigned int v[8];
#pragma unroll
    for (int j = 0; j < 8; ++j) v[j] = f2bf(W[(size_t)(k0 + j) * D + col]);
    uint4 o;
    o.x = v[0] | (v[1] << 16);
    o.y = v[2] | (v[3] << 16);
    o.z = v[4] | (v[5] << 16);
    o.w = v[6] | (v[7] << 16);
    pack[e] = o;
}

// ======== gemm tile body: z[row0..row0+127] = relu(x@W1+b1)@W2 (bf16) =======
// smem: 64KB. ws 32KB (W1 -> W2 -> z staging), xs4 32KB (swizzled x/h tile).
__device__ __forceinline__ void gemm_tile(
    char* smem, int row0,
    const float* __restrict__ xin, const uint4* __restrict__ wpack,
    const float* __restrict__ b1, uint4* __restrict__ zout4, int n_rows)
{
    const int t = threadIdx.x;
    uint4* ws  = (uint4*)smem;
    uint4* xs4 = ws + 2048;

#pragma unroll
    for (int i = 0; i < 8; ++i) ws[t + 256 * i] = wpack[t + 256 * i];

    const float4* g = (const float4*)xin;
#pragma unroll
    for (int i = 0; i < 8; ++i) {
        int c = t + 256 * i;              // 0..2047
        int row = c >> 4, kc = c & 15;
        int grow = row0 + row;
        if (grow < n_rows) {
            float4 f0 = g[(size_t)grow * 32 + kc * 2];
            float4 f1 = g[(size_t)grow * 32 + kc * 2 + 1];
            uint4 v;
            v.x = pack2(f0.x, f0.y);
            v.y = pack2(f0.z, f0.w);
            v.z = pack2(f1.x, f1.y);
            v.w = pack2(f1.z, f1.w);
            xs4[row * 16 + (kc ^ (row & 7))] = v;
        }
    }
    __syncthreads();

    const int l = t & 63;
    const int w = t >> 6;
    const int l15 = l & 15;
    const int lk = l >> 4;
    const int arow0 = w * 32 + l15;
    const int arow1 = arow0 + 16;

    float bias1[8];
#pragma unroll
    for (int nt = 0; nt < 8; ++nt) bias1[nt] = b1[nt * 16 + l15];

    f32x4 acc1[2][8];
#pragma unroll
    for (int rt = 0; rt < 2; ++rt)
#pragma unroll
        for (int nt = 0; nt < 8; ++nt) acc1[rt][nt] = (f32x4){0.f, 0.f, 0.f, 0.f};

#pragma unroll
    for (int kt = 0; kt < 4; ++kt) {
        int kc0 = kt * 4 + lk;
        short8x a0 = *(const short8x*)&xs4[arow0 * 16 + (kc0 ^ (arow0 & 7))];
        short8x a1 = *(const short8x*)&xs4[arow1 * 16 + (kc0 ^ (arow1 & 7))];
#pragma unroll
        for (int nt = 0; nt < 8; ++nt) {
            short8x bf = *(const short8x*)&ws[(kt * 8 + nt) * 64 + l];
            acc1[0][nt] = __builtin_amdgcn_mfma_f32_16x16x32_bf16(a0, bf, acc1[0][nt], 0, 0, 0);
            acc1[1][nt] = __builtin_amdgcn_mfma_f32_16x16x32_bf16(a1, bf, acc1[1][nt], 0, 0, 0);
        }
    }

    // h = relu(acc1+b1) -> overwrite own xs rows (wave-private). D layout:
    // col=l&15, row=(l>>4)*4+r  [m89-verified]
    unsigned short* hsu = (unsigned short*)xs4;
#pragma unroll
    for (int rt = 0; rt < 2; ++rt) {
#pragma unroll
        for (int nt = 0; nt < 8; ++nt) {
            int col = nt * 16 + l15;
            int ci = (col >> 3), ce2 = (col & 7);
#pragma unroll
            for (int r = 0; r < 4; ++r) {
                int rowl = w * 32 + rt * 16 + lk * 4 + r;
                float v = fmaxf(acc1[rt][nt][r] + bias1[nt], 0.f);
                hsu[(rowl * 16 + (ci ^ (rowl & 7))) * 8 + ce2] = (unsigned short)f2bf(v);
            }
        }
    }
    __syncthreads();   // W1 reads done -> overwrite ws with W2

#pragma unroll
    for (int i = 0; i < 8; ++i) ws[t + 256 * i] = wpack[2048 + t + 256 * i];
    __syncthreads();

    f32x4 acc2[2][8];
#pragma unroll
    for (int rt = 0; rt < 2; ++rt)
#pragma unroll
        for (int nt = 0; nt < 8; ++nt) acc2[rt][nt] = (f32x4){0.f, 0.f, 0.f, 0.f};

#pragma unroll
    for (int kt = 0; kt < 4; ++kt) {
        int kc0 = kt * 4 + lk;
        short8x a0 = *(const short8x*)&xs4[arow0 * 16 + (kc0 ^ (arow0 & 7))];
        short8x a1 = *(const short8x*)&xs4[arow1 * 16 + (kc0 ^ (arow1 & 7))];
#pragma unroll
        for (int nt = 0; nt < 8; ++nt) {
            short8x bf = *(const short8x*)&ws[(kt * 8 + nt) * 64 + l];
            acc2[0][nt] = __builtin_amdgcn_mfma_f32_16x16x32_bf16(a0, bf, acc2[0][nt], 0, 0, 0);
            acc2[1][nt] = __builtin_amdgcn_mfma_f32_16x16x32_bf16(a1, bf, acc2[1][nt], 0, 0, 0);
        }
    }
    __syncthreads();   // W2 reads done -> ws becomes z staging

    unsigned short* zls = (unsigned short*)ws;
#pragma unroll
    for (int rt = 0; rt < 2; ++rt) {
#pragma unroll
        for (int nt = 0; nt < 8; ++nt) {
            int col = nt * 16 + l15;
#pragma unroll
            for (int r = 0; r < 4; ++r) {
                int rowl = w * 32 + rt * 16 + lk * 4 + r;
                zls[rowl * D + col] = (unsigned short)f2bf(acc2[rt][nt][r]);
            }
        }
    }
    __syncthreads();
    const uint4* zlsv = (const uint4*)zls;
#pragma unroll
    for (int i = 0; i < 8; ++i) {
        int c = t + 256 * i;              // 0..2047
        int row = c >> 4, kc = c & 15;
        if (row0 + row < n_rows)
            zout4[(size_t)(row0 + row) * 16 + kc] = zlsv[c];
    }
}

// ========== Kernel A: bucket scatter (196 blocks) ∥ gemm part A =============
__global__ __launch_bounds__(256) void scatter_gemm(
    const int* __restrict__ esrc, const int* __restrict__ edst,
    int* __restrict__ gfill, unsigned* __restrict__ pairs,
    int* __restrict__ ovf_cnt, int2* __restrict__ ovf_list, int E, int NB,
    int nscatter,
    const float* __restrict__ xin, const uint4* __restrict__ wpack,
    const float* __restrict__ b1, uint4* __restrict__ zout4, int n_rows)
{
    __shared__ __align__(16) char smem[65536];
    const int t = threadIdx.x;

    if (blockIdx.x < nscatter) {
        int* lcnt  = (int*)smem;
        int* lbase = lcnt + NBMAX;
        for (int b = t; b < NB; b += 256) lcnt[b] = 0;
        __syncthreads();
        int cb = blockIdx.x * CHUNK;
        int ce = min(E, cb + CHUNK);
        for (int i = cb + t; i < ce; i += 256)
            atomicAdd(&lcnt[edst[i] >> 8], 1);
        __syncthreads();
        for (int b = t; b < NB; b += 256) {
            int c = lcnt[b];
            lbase[b] = c ? atomicAdd(&gfill[b], c) : 0;
            lcnt[b] = 0;
        }
        __syncthreads();
        for (int i = cb + t; i < ce; i += 256) {
            int d = edst[i];
            int s = esrc[i];
            int b = d >> 8;
            int pos = lbase[b] + atomicAdd(&lcnt[b], 1);
            if (pos < BKCAP) {
                pairs[(size_t)b * BKCAP + pos] = ((unsigned)s << 8) | (unsigned)(d & 255);
            } else {
                int o = atomicAdd(ovf_cnt, 1);
                if (o < OVF_CAP) ovf_list[o] = make_int2(s, d);
            }
        }
        return;
    }
    gemm_tile(smem, (blockIdx.x - nscatter) * 128, xin, wpack, b1, zout4, n_rows);
}

// ========== Kernel B: node_sort (NB blocks) ∥ gemm part B ===================
__global__ __launch_bounds__(256) void sort_gemm(
    const unsigned* __restrict__ pairs, const int* __restrict__ gfill,
    int* __restrict__ srcs, int2* __restrict__ noff2, int n_nodes, int nsort,
    const float* __restrict__ xin, const uint4* __restrict__ wpack,
    const float* __restrict__ b1, uint4* __restrict__ zout4, int n_rows,
    int gemm_blk0)
{
    __shared__ __align__(16) char smem[65536];
    const int t = threadIdx.x;

    if (blockIdx.x < (unsigned)nsort) {
        int* fill  = (int*)smem;
        int* scanb = fill + NPB;
        const int bkt = blockIdx.x;
        const size_t ebase = (size_t)bkt * BKCAP;
        const int ecnt = min(gfill[bkt], BKCAP);

        fill[t] = 0;
        __syncthreads();
        for (int i = t; i < ecnt; i += 256)
            atomicAdd(&fill[pairs[ebase + i] & 255], 1);
        __syncthreads();

        int c = fill[t];
        scanb[t] = c;
        __syncthreads();
        for (int s = 1; s < NPB; s <<= 1) {
            int add = (t >= s) ? scanb[t - s] : 0;
            __syncthreads();
            scanb[t] += add;
            __syncthreads();
        }
        int off = scanb[t] - c;               // exclusive
        int node = (bkt << 8) + t;
        if (node < n_nodes) noff2[node] = make_int2((int)ebase + off, c);
        fill[t] = off;
        __syncthreads();

        for (int i = t; i < ecnt; i += 256) {
            unsigned v = pairs[ebase + i];
            int pos = atomicAdd(&fill[v & 255], 1);
            srcs[ebase + pos] = (int)(v >> 8);
        }
        return;
    }
    gemm_tile(smem, (blockIdx.x - nsort + gemm_blk0) * 128, xin, wpack, b1, zout4, n_rows);
}

// ========== pull: out[n] = sum_{csr} z[src] + b2 (f32), 8-wide MLP ==========
// 32 lanes/node (uint2/lane), 8 nodes/block — best measured shape (70% occ).
__global__ __launch_bounds__(256) void pull_csr(
    const uint2* __restrict__ z2, const int* __restrict__ srcs,
    const int2* __restrict__ noff2, const float* __restrict__ b2,
    float* __restrict__ out, int n_nodes)
{
    int node = blockIdx.x * 8 + (threadIdx.x >> 5);
    int lane = threadIdx.x & 31;
    if (node >= n_nodes) return;
    int2 se = noff2[node];
    int i = se.x, end = se.x + se.y;

    float a0 = 0.f, a1 = 0.f, a2 = 0.f, a3 = 0.f;
    for (; i + 8 <= end; i += 8) {
        int4 sA = *(const int4*)(srcs + i);
        int4 sB = *(const int4*)(srcs + i + 4);
        uint2 v0 = z2[(size_t)sA.x * 32 + lane];
        uint2 v1 = z2[(size_t)sA.y * 32 + lane];
        uint2 v2 = z2[(size_t)sA.z * 32 + lane];
        uint2 v3 = z2[(size_t)sA.w * 32 + lane];
        uint2 v4 = z2[(size_t)sB.x * 32 + lane];
        uint2 v5 = z2[(size_t)sB.y * 32 + lane];
        uint2 v6 = z2[(size_t)sB.z * 32 + lane];
        uint2 v7 = z2[(size_t)sB.w * 32 + lane];
        a0 += bflo(v0.x) + bflo(v1.x) + bflo(v2.x) + bflo(v3.x)
            + bflo(v4.x) + bflo(v5.x) + bflo(v6.x) + bflo(v7.x);
        a1 += bfhi(v0.x) + bfhi(v1.x) + bfhi(v2.x) + bfhi(v3.x)
            + bfhi(v4.x) + bfhi(v5.x) + bfhi(v6.x) + bfhi(v7.x);
        a2 += bflo(v0.y) + bflo(v1.y) + bflo(v2.y) + bflo(v3.y)
            + bflo(v4.y) + bflo(v5.y) + bflo(v6.y) + bflo(v7.y);
        a3 += bfhi(v0.y) + bfhi(v1.y) + bfhi(v2.y) + bfhi(v3.y)
            + bfhi(v4.y) + bfhi(v5.y) + bfhi(v6.y) + bfhi(v7.y);
    }
    if (i + 4 <= end) {
        int4 s = *(const int4*)(srcs + i);
        uint2 v0 = z2[(size_t)s.x * 32 + lane];
        uint2 v1 = z2[(size_t)s.y * 32 + lane];
        uint2 v2 = z2[(size_t)s.z * 32 + lane];
        uint2 v3 = z2[(size_t)s.w * 32 + lane];
        a0 += bflo(v0.x) + bflo(v1.x) + bflo(v2.x) + bflo(v3.x);
        a1 += bfhi(v0.x) + bfhi(v1.x) + bfhi(v2.x) + bfhi(v3.x);
        a2 += bflo(v0.y) + bflo(v1.y) + bflo(v2.y) + bflo(v3.y);
        a3 += bfhi(v0.y) + bfhi(v1.y) + bfhi(v2.y) + bfhi(v3.y);
        i += 4;
    }
    for (; i < end; ++i) {
        int s = srcs[i];
        uint2 v = z2[(size_t)s * 32 + lane];
        a0 += bflo(v.x); a1 += bfhi(v.x);
        a2 += bflo(v.y); a3 += bfhi(v.y);
    }
    float4 bv = ((const float4*)b2)[lane];
    ((float4*)out)[(size_t)node * 32 + lane] =
        make_float4(a0 + bv.x, a1 + bv.y, a2 + bv.z, a3 + bv.w);
}

// Overflow edges (normally zero): out[d] += z[s], f32 atomics.
__global__ __launch_bounds__(32) void ovf_f32(
    const int* __restrict__ ovf_cnt, const int2* __restrict__ ovf_list,
    const uint2* __restrict__ z2, float* __restrict__ out)
{
    int n = *ovf_cnt;
    if (n > OVF_CAP) n = OVF_CAP;
    int lane = threadIdx.x;
    for (int i = blockIdx.x; i < n; i += gridDim.x) {
        int2 sd = ovf_list[i];
        uint2 v = z2[(size_t)sd.x * 32 + lane];
        unsafeAtomicAdd(&out[(size_t)sd.y * D + lane * 4 + 0], bflo(v.x));
        unsafeAtomicAdd(&out[(size_t)sd.y * D + lane * 4 + 1], bfhi(v.x));
        unsafeAtomicAdd(&out[(size_t)sd.y * D + lane * 4 + 2], bflo(v.y));
        unsafeAtomicAdd(&out[(size_t)sd.y * D + lane * 4 + 3], bfhi(v.y));
    }
}

// ================= fallback path (f32 atomic scatter) =================
template <bool RELU>
__global__ __launch_bounds__(256) void gemm_bias_act(
    const float* xin, const float* __restrict__ W,
    const float* __restrict__ b, float* xout, int n_rows)
{
    __shared__ float Ws[D * D];
    __shared__ float xs[32 * D];
    const int t = threadIdx.x;
    const int row0 = blockIdx.x * 32;
    const float4* Wv = (const float4*)W;
    float4* Wsv = (float4*)Ws;
#pragma unroll
    for (int i = 0; i < 16; ++i) Wsv[t + 256 * i] = Wv[t + 256 * i];
    const float4* xv = (const float4*)xin;
    float4* xsv = (float4*)xs;
#pragma unroll
    for (int i = 0; i < 4; ++i) {
        int f4 = t + 256 * i;
        int row = row0 + (f4 >> 5);
        if (row < n_rows) xsv[f4] = xv[(size_t)row0 * 32 + f4];
    }
    __syncthreads();
    const int cg = t & 31;
    const int rg = t >> 5;
    float4 bias = ((const float4*)b)[cg];
    float4 acc[4];
#pragma unroll
    for (int ri = 0; ri < 4; ++ri) acc[ri] = make_float4(0.f, 0.f, 0.f, 0.f);
#pragma unroll 4
    for (int k = 0; k < D; k += 4) {
        float4 w0 = Wsv[(k + 0) * 32 + cg];
        float4 w1 = Wsv[(k + 1) * 32 + cg];
        float4 w2 = Wsv[(k + 2) * 32 + cg];
        float4 w3 = Wsv[(k + 3) * 32 + cg];
#pragma unroll
        for (int ri = 0; ri < 4; ++ri) {
            float4 xa = xsv[(rg + 8 * ri) * 32 + (k >> 2)];
            acc[ri].x = fmaf(xa.x, w0.x, fmaf(xa.y, w1.x, fmaf(xa.z, w2.x, fmaf(xa.w, w3.x, acc[ri].x))));
            acc[ri].y = fmaf(xa.x, w0.y, fmaf(xa.y, w1.y, fmaf(xa.z, w2.y, fmaf(xa.w, w3.y, acc[ri].y))));
            acc[ri].z = fmaf(xa.x, w0.z, fmaf(xa.y, w1.z, fmaf(xa.z, w2.z, fmaf(xa.w, w3.z, acc[ri].z))));
            acc[ri].w = fmaf(xa.x, w0.w, fmaf(xa.y, w1.w, fmaf(xa.z, w2.w, fmaf(xa.w, w3.w, acc[ri].w))));
        }
    }
#pragma unroll
    for (int ri = 0; ri < 4; ++ri) {
        int row = row0 + rg + 8 * ri;
        if (row >= n_rows) continue;
        float4 o;
        o.x = acc[ri].x + bias.x; o.y = acc[ri].y + bias.y;
        o.z = acc[ri].z + bias.z; o.w = acc[ri].w + bias.w;
        if (RELU) {
            o.x = fmaxf(o.x, 0.f); o.y = fmaxf(o.y, 0.f);
            o.z = fmaxf(o.z, 0.f); o.w = fmaxf(o.w, 0.f);
        }
        ((float4*)xout)[(size_t)row * 32 + cg] = o;
    }
}

__global__ __launch_bounds__(256) void zero_kernel(float4* p, int n4)
{
    int i = blockIdx.x * 256 + threadIdx.x;
    int stride = gridDim.x * 256;
    for (; i < n4; i += stride) p[i] = make_float4(0.f, 0.f, 0.f, 0.f);
}

__global__ __launch_bounds__(256) void scatter_kernel(
    const float* __restrict__ h, const int* __restrict__ esrc,
    const int* __restrict__ edst, float* __restrict__ agg, long n_items)
{
    long idx = (long)blockIdx.x * 256 + threadIdx.x;
    long stride = (long)gridDim.x * 256;
    for (; idx < n_items; idx += stride) {
        int e = (int)(idx >> 7);
        int c = (int)(idx & 127);
        int s = esrc[e];
        int d = edst[e];
        unsafeAtomicAdd(&agg[(size_t)d * D + c], h[(size_t)s * D + c]);
    }
}

extern "C" void kernel_launch(void* const* d_in, const int* in_sizes, int n_in,
                              void* d_out, int out_size, void* d_ws, size_t ws_size,
                              hipStream_t stream)
{
    const float* x    = (const float*)d_in[0];
    const int*   esrc = (const int*)d_in[1];
    const int*   edst = (const int*)d_in[2];
    const float* W1   = (const float*)d_in[3];
    const float* b1   = (const float*)d_in[4];
    const float* W2   = (const float*)d_in[5];
    const float* b2   = (const float*)d_in[6];
    float* out = (float*)d_out;

    const int N = in_sizes[0] / D;   // 100000
    const int E = in_sizes[1];       // 1600000
    const int NB = (N + NPB - 1) / NPB;   // 391

    char* ws = (char*)d_ws;
    size_t off_z     = 0;                                        // z: 25.6 MB
    size_t off_pairs = off_z + (size_t)N * 256;
    size_t off_srcs  = off_pairs + (size_t)NBMAX * BKCAP * 4;    // 16.8 MB
    size_t off_noff  = off_srcs + (size_t)NBMAX * BKCAP * 4;     // 16.8 MB
    size_t off_gfill = (off_noff + (size_t)N * 8 + 255) & ~(size_t)255;
    size_t off_ovfc  = off_gfill + NBMAX * 4;
    size_t off_ovfl  = off_ovfc + 16;
    size_t off_pack  = (off_ovfl + (size_t)OVF_CAP * 8 + 255) & ~(size_t)255;
    size_t need      = off_pack + 65536;

    const int gchunk  = (E + CHUNK - 1) / CHUNK;   // 196
    const int nblk128 = (N + 127) / 128;           // 782
    const int gemmA   = (nblk128 * 3) / 5;         // ~469 (overlaps scatter)
    const int gemmB   = nblk128 - gemmA;           // ~313 (overlaps node_sort)

    if (ws_size >= need && N <= NBMAX * NPB) {
        uint4*    z4    = (uint4*)(ws + off_z);
        unsigned* pairs = (unsigned*)(ws + off_pairs);
        int*      srcs  = (int*)(ws + off_srcs);
        int2*     noff2 = (int2*)(ws + off_noff);
        int*      gfill = (int*)(ws + off_gfill);
        int*      ovfc  = (int*)(ws + off_ovfc);
        int2*     ovfl  = (int2*)(ws + off_ovfl);
        uint4*    pack  = (uint4*)(ws + off_pack);

        // 0) pack weights; block 16 zeroes gfill+ovfc (NBMAX+4 ints)
        pack_w<<<17, 256, 0, stream>>>(W1, W2, pack, gfill, NBMAX + 4);

        // 1) scatter (196) ∥ gemm rows [0, gemmA*128)
        scatter_gemm<<<gchunk + gemmA, 256, 0, stream>>>(
            esrc, edst, gfill, pairs, ovfc, ovfl, E, NB, gchunk,
            x, pack, b1, z4, N);

        // 2) node_sort (391) ∥ gemm rows [gemmA*128, N)
        sort_gemm<<<NB + gemmB, 256, 0, stream>>>(
            pairs, gfill, srcs, noff2, N, NB,
            x, pack, b1, z4, N, gemmA);

        // 3) out[n] = sum z[src] + b2 (f32 gather, 8-deep MLP)
        pull_csr<<<(N + 7) / 8, 256, 0, stream>>>(
            (const uint2*)z4, srcs, noff2, b2, out, N);

        // 4) overflow edges (normally zero)
        ovf_f32<<<8, 32, 0, stream>>>(ovfc, ovfl, (const uint2*)z4, out);
    } else {
        float* h = (float*)ws;
        const int nb32 = (N + 31) / 32;
        gemm_bias_act<true><<<nb32, 256, 0, stream>>>(x, W1, b1, h, N);
        zero_kernel<<<2048, 256, 0, stream>>>((float4*)out, N * D / 4);
        scatter_kernel<<<8192, 256, 0, stream>>>(h, esrc, edst, out, (long)E * D);
        gemm_bias_act<false><<<nb32, 256, 0, stream>>>(out, W2, b2, out, N);
    }
}

// Round 13
// 113.021 us; speedup vs baseline: 1.0996x; 1.0996x over previous
//
#include <hip/hip_runtime.h>

#define D 128
#define NPB 256            // nodes per bucket (dst>>8)
#define NBMAX 512          // max buckets (N <= 131072)
#define BKCAP 8192         // edge capacity per bucket (mean 4096, +64 sigma)
#define CHUNK 8192         // edges per scatter block
#define OVF_CAP 8192

typedef __attribute__((ext_vector_type(8))) short short8x;
typedef __attribute__((ext_vector_type(4))) float f32x4;

// ---- bf16 helpers (manual RNE) ----
__device__ inline unsigned int f2bf(float f) {
    unsigned int u = __builtin_bit_cast(unsigned int, f);
    return (u + 0x7fffu + ((u >> 16) & 1u)) >> 16;
}
__device__ inline float bflo(unsigned int v) {
    return __builtin_bit_cast(float, v << 16);
}
__device__ inline float bfhi(unsigned int v) {
    return __builtin_bit_cast(float, v & 0xffff0000u);
}
__device__ inline unsigned int pack2(float lo, float hi) {
    return f2bf(lo) | (f2bf(hi) << 16);
}

// ========= W pre-pack (+ block 16 zeroes gfill/ovfc) =========
__global__ __launch_bounds__(256) void pack_w(
    const float* __restrict__ W1, const float* __restrict__ W2,
    uint4* __restrict__ pack, int* __restrict__ zero_area, int nz)
{
    if (blockIdx.x == 16) {
        for (int i = threadIdx.x; i < nz; i += 256) zero_area[i] = 0;
        return;
    }
    int e = blockIdx.x * 256 + threadIdx.x;      // 0..4095
    const float* W = (e & 2048) ? W2 : W1;
    int f = (e >> 6) & 31, l = e & 63;
    int kt = f >> 3, nt = f & 7;
    int k0 = kt * 32 + (l >> 4) * 8;
    int col = nt * 16 + (l & 15);
    unsigned int v[8];
#pragma unroll
    for (int j = 0; j < 8; ++j) v[j] = f2bf(W[(size_t)(k0 + j) * D + col]);
    uint4 o;
    o.x = v[0] | (v[1] << 16);
    o.y = v[2] | (v[3] << 16);
    o.z = v[4] | (v[5] << 16);
    o.w = v[6] | (v[7] << 16);
    pack[e] = o;
}

// ========== FUSED: bucket_scatter (196) ∥ gemm all rows (782) — R11 best ====
__global__ __launch_bounds__(256) void build_gemm(
    const int* __restrict__ esrc, const int* __restrict__ edst,
    int* __restrict__ gfill, unsigned* __restrict__ pairs,
    int* __restrict__ ovf_cnt, int2* __restrict__ ovf_list, int E, int NB,
    int nscatter,
    const float* __restrict__ xin, const uint4* __restrict__ wpack,
    const float* __restrict__ b1, uint4* __restrict__ zout4, int n_rows)
{
    __shared__ __align__(16) char smem[65536];
    const int t = threadIdx.x;

    if (blockIdx.x < nscatter) {
        // ---------------- bucket scatter ----------------
        int* lcnt  = (int*)smem;
        int* lbase = lcnt + NBMAX;
        for (int b = t; b < NB; b += 256) lcnt[b] = 0;
        __syncthreads();
        int cb = blockIdx.x * CHUNK;
        int ce = min(E, cb + CHUNK);
        for (int i = cb + t; i < ce; i += 256)
            atomicAdd(&lcnt[edst[i] >> 8], 1);
        __syncthreads();
        for (int b = t; b < NB; b += 256) {
            int c = lcnt[b];
            lbase[b] = c ? atomicAdd(&gfill[b], c) : 0;
            lcnt[b] = 0;
        }
        __syncthreads();
        for (int i = cb + t; i < ce; i += 256) {
            int d = edst[i];
            int s = esrc[i];
            int b = d >> 8;
            int pos = lbase[b] + atomicAdd(&lcnt[b], 1);
            if (pos < BKCAP) {
                pairs[(size_t)b * BKCAP + pos] = ((unsigned)s << 8) | (unsigned)(d & 255);
            } else {
                int o = atomicAdd(ovf_cnt, 1);
                if (o < OVF_CAP) ovf_list[o] = make_int2(s, d);
            }
        }
        return;
    }

    // ---------------- fused GEMM: z = relu(x@W1+b1)@W2, 128-row tile --------
    uint4* ws  = (uint4*)smem;          // 32KB: W1 -> W2 -> z staging
    uint4* xs4 = ws + 2048;             // 32KB: 128 rows x 16 uint4, swizzled
    const int row0 = (blockIdx.x - nscatter) * 128;

#pragma unroll
    for (int i = 0; i < 8; ++i) ws[t + 256 * i] = wpack[t + 256 * i];

    const float4* g = (const float4*)xin;
#pragma unroll
    for (int i = 0; i < 8; ++i) {
        int c = t + 256 * i;              // 0..2047
        int row = c >> 4, kc = c & 15;
        int grow = row0 + row;
        if (grow < n_rows) {
            float4 f0 = g[(size_t)grow * 32 + kc * 2];
            float4 f1 = g[(size_t)grow * 32 + kc * 2 + 1];
            uint4 v;
            v.x = pack2(f0.x, f0.y);
            v.y = pack2(f0.z, f0.w);
            v.z = pack2(f1.x, f1.y);
            v.w = pack2(f1.z, f1.w);
            xs4[row * 16 + (kc ^ (row & 7))] = v;
        }
    }
    __syncthreads();

    const int l = t & 63;
    const int w = t >> 6;
    const int l15 = l & 15;
    const int lk = l >> 4;
    const int arow0 = w * 32 + l15;
    const int arow1 = arow0 + 16;

    float bias1[8];
#pragma unroll
    for (int nt = 0; nt < 8; ++nt) bias1[nt] = b1[nt * 16 + l15];

    f32x4 acc1[2][8];
#pragma unroll
    for (int rt = 0; rt < 2; ++rt)
#pragma unroll
        for (int nt = 0; nt < 8; ++nt) acc1[rt][nt] = (f32x4){0.f, 0.f, 0.f, 0.f};

#pragma unroll
    for (int kt = 0; kt < 4; ++kt) {
        int kc0 = kt * 4 + lk;
        short8x a0 = *(const short8x*)&xs4[arow0 * 16 + (kc0 ^ (arow0 & 7))];
        short8x a1 = *(const short8x*)&xs4[arow1 * 16 + (kc0 ^ (arow1 & 7))];
#pragma unroll
        for (int nt = 0; nt < 8; ++nt) {
            short8x bf = *(const short8x*)&ws[(kt * 8 + nt) * 64 + l];
            acc1[0][nt] = __builtin_amdgcn_mfma_f32_16x16x32_bf16(a0, bf, acc1[0][nt], 0, 0, 0);
            acc1[1][nt] = __builtin_amdgcn_mfma_f32_16x16x32_bf16(a1, bf, acc1[1][nt], 0, 0, 0);
        }
    }

    // h = relu(acc1+b1) -> own xs rows (wave-private). D layout: col=l&15,
    // row=(l>>4)*4+r  [m89-verified]
    unsigned short* hsu = (unsigned short*)xs4;
#pragma unroll
    for (int rt = 0; rt < 2; ++rt) {
#pragma unroll
        for (int nt = 0; nt < 8; ++nt) {
            int col = nt * 16 + l15;
            int ci = (col >> 3), ce2 = (col & 7);
#pragma unroll
            for (int r = 0; r < 4; ++r) {
                int rowl = w * 32 + rt * 16 + lk * 4 + r;
                float v = fmaxf(acc1[rt][nt][r] + bias1[nt], 0.f);
                hsu[(rowl * 16 + (ci ^ (rowl & 7))) * 8 + ce2] = (unsigned short)f2bf(v);
            }
        }
    }
    __syncthreads();   // W1 reads done -> overwrite ws with W2

#pragma unroll
    for (int i = 0; i < 8; ++i) ws[t + 256 * i] = wpack[2048 + t + 256 * i];
    __syncthreads();

    f32x4 acc2[2][8];
#pragma unroll
    for (int rt = 0; rt < 2; ++rt)
#pragma unroll
        for (int nt = 0; nt < 8; ++nt) acc2[rt][nt] = (f32x4){0.f, 0.f, 0.f, 0.f};

#pragma unroll
    for (int kt = 0; kt < 4; ++kt) {
        int kc0 = kt * 4 + lk;
        short8x a0 = *(const short8x*)&xs4[arow0 * 16 + (kc0 ^ (arow0 & 7))];
        short8x a1 = *(const short8x*)&xs4[arow1 * 16 + (kc0 ^ (arow1 & 7))];
#pragma unroll
        for (int nt = 0; nt < 8; ++nt) {
            short8x bf = *(const short8x*)&ws[(kt * 8 + nt) * 64 + l];
            acc2[0][nt] = __builtin_amdgcn_mfma_f32_16x16x32_bf16(a0, bf, acc2[0][nt], 0, 0, 0);
            acc2[1][nt] = __builtin_amdgcn_mfma_f32_16x16x32_bf16(a1, bf, acc2[1][nt], 0, 0, 0);
        }
    }
    __syncthreads();   // W2 reads done -> ws becomes z staging

    unsigned short* zls = (unsigned short*)ws;
#pragma unroll
    for (int rt = 0; rt < 2; ++rt) {
#pragma unroll
        for (int nt = 0; nt < 8; ++nt) {
            int col = nt * 16 + l15;
#pragma unroll
            for (int r = 0; r < 4; ++r) {
                int rowl = w * 32 + rt * 16 + lk * 4 + r;
                zls[rowl * D + col] = (unsigned short)f2bf(acc2[rt][nt][r]);
            }
        }
    }
    __syncthreads();
    const uint4* zlsv = (const uint4*)zls;
#pragma unroll
    for (int i = 0; i < 8; ++i) {
        int c = t + 256 * i;              // 0..2047
        int row = c >> 4, kc = c & 15;
        if (row0 + row < n_rows)
            zout4[(size_t)(row0 + row) * 16 + kc] = zlsv[c];
    }
}

// ========== FUSED sort+pull: one 1024-thread block per bucket ===============
// Counting-sort the bucket's pairs in LDS (pairs read ONCE into 8 static
// regs/thread), then gather z rows and write out += b2. Kills the node_sort
// dispatch and the srcs/noff2 global round-trip.
__global__ __launch_bounds__(1024) void sort_pull(
    const unsigned* __restrict__ pairs, const int* __restrict__ gfill,
    const uint2* __restrict__ z2, const float* __restrict__ b2,
    float* __restrict__ out, int n_nodes)
{
    __shared__ int srcl[BKCAP];        // 32 KB sorted src list
    __shared__ int off[NPB + 1];
    __shared__ int fill[NPB];
    __shared__ int scanb[NPB];

    const int bkt = blockIdx.x;
    const int t = threadIdx.x;
    const size_t ebase = (size_t)bkt * BKCAP;
    const int ecnt = min(gfill[bkt], BKCAP);

    if (t < NPB) fill[t] = 0;
    __syncthreads();

    // pairs -> 8 static registers + LDS histogram (rule #20: static idx only)
    unsigned pv0, pv1, pv2, pv3, pv4, pv5, pv6, pv7;
#define LOADP(K, PV) { int i = t + (K) * 1024; \
        PV = (i < ecnt) ? pairs[ebase + i] : 0xFFFFFFFFu; \
        if (i < ecnt) atomicAdd(&fill[PV & 255], 1); }
    LOADP(0, pv0) LOADP(1, pv1) LOADP(2, pv2) LOADP(3, pv3)
    LOADP(4, pv4) LOADP(5, pv5) LOADP(6, pv6) LOADP(7, pv7)
#undef LOADP
    __syncthreads();

    if (t < NPB) scanb[t] = fill[t];
    __syncthreads();
    for (int s = 1; s < NPB; s <<= 1) {
        int add = 0;
        if (t < NPB && t >= s) add = scanb[t - s];
        __syncthreads();
        if (t < NPB) scanb[t] += add;
        __syncthreads();
    }
    if (t < NPB) {
        int c = fill[t];
        off[t] = scanb[t] - c;
        fill[t] = scanb[t] - c;
    }
    if (t == 0) off[NPB] = ecnt;
    __syncthreads();

#define SCATP(K, PV) { int i = t + (K) * 1024; \
        if (i < ecnt) { int pos = atomicAdd(&fill[PV & 255], 1); \
            srcl[pos] = (int)(PV >> 8); } }
    SCATP(0, pv0) SCATP(1, pv1) SCATP(2, pv2) SCATP(3, pv3)
    SCATP(4, pv4) SCATP(5, pv5) SCATP(6, pv6) SCATP(7, pv7)
#undef SCATP
    __syncthreads();

    // gather: 32 lane-groups x 8 nodes each, 8-wide MLP inner loop
    const int grp = t >> 5;
    const int lane = t & 31;
    float4 bv = ((const float4*)b2)[lane];

    for (int ln = grp; ln < NPB; ln += 32) {
        int node = (bkt << 8) + ln;
        if (node >= n_nodes) break;
        int i = off[ln], end = off[ln + 1];

        float a0 = 0.f, a1 = 0.f, a2 = 0.f, a3 = 0.f;
        for (; i + 8 <= end; i += 8) {
            int s0 = srcl[i],     s1 = srcl[i + 1], s2 = srcl[i + 2], s3 = srcl[i + 3];
            int s4 = srcl[i + 4], s5 = srcl[i + 5], s6 = srcl[i + 6], s7 = srcl[i + 7];
            uint2 v0 = z2[(size_t)s0 * 32 + lane];
            uint2 v1 = z2[(size_t)s1 * 32 + lane];
            uint2 v2 = z2[(size_t)s2 * 32 + lane];
            uint2 v3 = z2[(size_t)s3 * 32 + lane];
            uint2 v4 = z2[(size_t)s4 * 32 + lane];
            uint2 v5 = z2[(size_t)s5 * 32 + lane];
            uint2 v6 = z2[(size_t)s6 * 32 + lane];
            uint2 v7 = z2[(size_t)s7 * 32 + lane];
            a0 += bflo(v0.x) + bflo(v1.x) + bflo(v2.x) + bflo(v3.x)
                + bflo(v4.x) + bflo(v5.x) + bflo(v6.x) + bflo(v7.x);
            a1 += bfhi(v0.x) + bfhi(v1.x) + bfhi(v2.x) + bfhi(v3.x)
                + bfhi(v4.x) + bfhi(v5.x) + bfhi(v6.x) + bfhi(v7.x);
            a2 += bflo(v0.y) + bflo(v1.y) + bflo(v2.y) + bflo(v3.y)
                + bflo(v4.y) + bflo(v5.y) + bflo(v6.y) + bflo(v7.y);
            a3 += bfhi(v0.y) + bfhi(v1.y) + bfhi(v2.y) + bfhi(v3.y)
                + bfhi(v4.y) + bfhi(v5.y) + bfhi(v6.y) + bfhi(v7.y);
        }
        if (i + 4 <= end) {
            int s0 = srcl[i], s1 = srcl[i + 1], s2 = srcl[i + 2], s3 = srcl[i + 3];
            uint2 v0 = z2[(size_t)s0 * 32 + lane];
            uint2 v1 = z2[(size_t)s1 * 32 + lane];
            uint2 v2 = z2[(size_t)s2 * 32 + lane];
            uint2 v3 = z2[(size_t)s3 * 32 + lane];
            a0 += bflo(v0.x) + bflo(v1.x) + bflo(v2.x) + bflo(v3.x);
            a1 += bfhi(v0.x) + bfhi(v1.x) + bfhi(v2.x) + bfhi(v3.x);
            a2 += bflo(v0.y) + bflo(v1.y) + bflo(v2.y) + bflo(v3.y);
            a3 += bfhi(v0.y) + bfhi(v1.y) + bfhi(v2.y) + bfhi(v3.y);
            i += 4;
        }
        for (; i < end; ++i) {
            uint2 v = z2[(size_t)srcl[i] * 32 + lane];
            a0 += bflo(v.x); a1 += bfhi(v.x);
            a2 += bflo(v.y); a3 += bfhi(v.y);
        }
        ((float4*)out)[(size_t)node * 32 + lane] =
            make_float4(a0 + bv.x, a1 + bv.y, a2 + bv.z, a3 + bv.w);
    }
}

// Overflow edges (normally zero): out[d] += z[s], f32 atomics.
__global__ __launch_bounds__(32) void ovf_f32(
    const int* __restrict__ ovf_cnt, const int2* __restrict__ ovf_list,
    const uint2* __restrict__ z2, float* __restrict__ out)
{
    int n = *ovf_cnt;
    if (n > OVF_CAP) n = OVF_CAP;
    int lane = threadIdx.x;
    for (int i = blockIdx.x; i < n; i += gridDim.x) {
        int2 sd = ovf_list[i];
        uint2 v = z2[(size_t)sd.x * 32 + lane];
        unsafeAtomicAdd(&out[(size_t)sd.y * D + lane * 4 + 0], bflo(v.x));
        unsafeAtomicAdd(&out[(size_t)sd.y * D + lane * 4 + 1], bfhi(v.x));
        unsafeAtomicAdd(&out[(size_t)sd.y * D + lane * 4 + 2], bflo(v.y));
        unsafeAtomicAdd(&out[(size_t)sd.y * D + lane * 4 + 3], bfhi(v.y));
    }
}

// ================= fallback path (f32 atomic scatter) =================
template <bool RELU>
__global__ __launch_bounds__(256) void gemm_bias_act(
    const float* xin, const float* __restrict__ W,
    const float* __restrict__ b, float* xout, int n_rows)
{
    __shared__ float Ws[D * D];
    __shared__ float xs[32 * D];
    const int t = threadIdx.x;
    const int row0 = blockIdx.x * 32;
    const float4* Wv = (const float4*)W;
    float4* Wsv = (float4*)Ws;
#pragma unroll
    for (int i = 0; i < 16; ++i) Wsv[t + 256 * i] = Wv[t + 256 * i];
    const float4* xv = (const float4*)xin;
    float4* xsv = (float4*)xs;
#pragma unroll
    for (int i = 0; i < 4; ++i) {
        int f4 = t + 256 * i;
        int row = row0 + (f4 >> 5);
        if (row < n_rows) xsv[f4] = xv[(size_t)row0 * 32 + f4];
    }
    __syncthreads();
    const int cg = t & 31;
    const int rg = t >> 5;
    float4 bias = ((const float4*)b)[cg];
    float4 acc[4];
#pragma unroll
    for (int ri = 0; ri < 4; ++ri) acc[ri] = make_float4(0.f, 0.f, 0.f, 0.f);
#pragma unroll 4
    for (int k = 0; k < D; k += 4) {
        float4 w0 = Wsv[(k + 0) * 32 + cg];
        float4 w1 = Wsv[(k + 1) * 32 + cg];
        float4 w2 = Wsv[(k + 2) * 32 + cg];
        float4 w3 = Wsv[(k + 3) * 32 + cg];
#pragma unroll
        for (int ri = 0; ri < 4; ++ri) {
            float4 xa = xsv[(rg + 8 * ri) * 32 + (k >> 2)];
            acc[ri].x = fmaf(xa.x, w0.x, fmaf(xa.y, w1.x, fmaf(xa.z, w2.x, fmaf(xa.w, w3.x, acc[ri].x))));
            acc[ri].y = fmaf(xa.x, w0.y, fmaf(xa.y, w1.y, fmaf(xa.z, w2.y, fmaf(xa.w, w3.y, acc[ri].y))));
            acc[ri].z = fmaf(xa.x, w0.z, fmaf(xa.y, w1.z, fmaf(xa.z, w2.z, fmaf(xa.w, w3.z, acc[ri].z))));
            acc[ri].w = fmaf(xa.x, w0.w, fmaf(xa.y, w1.w, fmaf(xa.z, w2.w, fmaf(xa.w, w3.w, acc[ri].w))));
        }
    }
#pragma unroll
    for (int ri = 0; ri < 4; ++ri) {
        int row = row0 + rg + 8 * ri;
        if (row >= n_rows) continue;
        float4 o;
        o.x = acc[ri].x + bias.x; o.y = acc[ri].y + bias.y;
        o.z = acc[ri].z + bias.z; o.w = acc[ri].w + bias.w;
        if (RELU) {
            o.x = fmaxf(o.x, 0.f); o.y = fmaxf(o.y, 0.f);
            o.z = fmaxf(o.z, 0.f); o.w = fmaxf(o.w, 0.f);
        }
        ((float4*)xout)[(size_t)row * 32 + cg] = o;
    }
}

__global__ __launch_bounds__(256) void zero_kernel(float4* p, int n4)
{
    int i = blockIdx.x * 256 + threadIdx.x;
    int stride = gridDim.x * 256;
    for (; i < n4; i += stride) p[i] = make_float4(0.f, 0.f, 0.f, 0.f);
}

__global__ __launch_bounds__(256) void scatter_kernel(
    const float* __restrict__ h, const int* __restrict__ esrc,
    const int* __restrict__ edst, float* __restrict__ agg, long n_items)
{
    long idx = (long)blockIdx.x * 256 + threadIdx.x;
    long stride = (long)gridDim.x * 256;
    for (; idx < n_items; idx += stride) {
        int e = (int)(idx >> 7);
        int c = (int)(idx & 127);
        int s = esrc[e];
        int d = edst[e];
        unsafeAtomicAdd(&agg[(size_t)d * D + c], h[(size_t)s * D + c]);
    }
}

extern "C" void kernel_launch(void* const* d_in, const int* in_sizes, int n_in,
                              void* d_out, int out_size, void* d_ws, size_t ws_size,
                              hipStream_t stream)
{
    const float* x    = (const float*)d_in[0];
    const int*   esrc = (const int*)d_in[1];
    const int*   edst = (const int*)d_in[2];
    const float* W1   = (const float*)d_in[3];
    const float* b1   = (const float*)d_in[4];
    const float* W2   = (const float*)d_in[5];
    const float* b2   = (const float*)d_in[6];
    float* out = (float*)d_out;

    const int N = in_sizes[0] / D;   // 100000
    const int E = in_sizes[1];       // 1600000
    const int NB = (N + NPB - 1) / NPB;   // 391

    char* ws = (char*)d_ws;
    size_t off_z     = 0;                                        // z: 25.6 MB
    size_t off_pairs = off_z + (size_t)N * 256;
    size_t off_gfill = (off_pairs + (size_t)NBMAX * BKCAP * 4 + 255) & ~(size_t)255;
    size_t off_ovfc  = off_gfill + NBMAX * 4;
    size_t off_ovfl  = off_ovfc + 16;
    size_t off_pack  = (off_ovfl + (size_t)OVF_CAP * 8 + 255) & ~(size_t)255;
    size_t need      = off_pack + 65536;

    const int gchunk  = (E + CHUNK - 1) / CHUNK;   // 196
    const int nblk128 = (N + 127) / 128;           // 782

    if (ws_size >= need && N <= NBMAX * NPB) {
        uint4*    z4    = (uint4*)(ws + off_z);
        unsigned* pairs = (unsigned*)(ws + off_pairs);
        int*      gfill = (int*)(ws + off_gfill);
        int*      ovfc  = (int*)(ws + off_ovfc);
        int2*     ovfl  = (int2*)(ws + off_ovfl);
        uint4*    pack  = (uint4*)(ws + off_pack);

        // 0) pack weights; block 16 zeroes gfill+ovfc (NBMAX+4 ints)
        pack_w<<<17, 256, 0, stream>>>(W1, W2, pack, gfill, NBMAX + 4);

        // 1) FUSED: edge bucketing (196 blocks) ∥ z=relu(x@W1+b1)@W2 (782)
        build_gemm<<<gchunk + nblk128, 256, 0, stream>>>(
            esrc, edst, gfill, pairs, ovfc, ovfl, E, NB, gchunk,
            x, pack, b1, z4, N);

        // 2) FUSED per-bucket LDS counting-sort + gather (out = segsum + b2)
        sort_pull<<<NB, 1024, 0, stream>>>(
            pairs, gfill, (const uint2*)z4, b2, out, N);

        // 3) overflow edges (normally zero)
        ovf_f32<<<8, 32, 0, stream>>>(ovfc, ovfl, (const uint2*)z4, out);
    } else {
        float* h = (float*)ws;
        const int nb32 = (N + 31) / 32;
        gemm_bias_act<true><<<nb32, 256, 0, stream>>>(x, W1, b1, h, N);
        zero_kernel<<<2048, 256, 0, stream>>>((float4*)out, N * D / 4);
        scatter_kernel<<<8192, 256, 0, stream>>>(h, esrc, edst, out, (long)E * D);
        gemm_bias_act<false><<<nb32, 256, 0, stream>>>(out, W2, b2, out, N);
    }
}